// Round 1
// baseline (400.759 us; speedup 1.0000x reference)
//
#include <hip/hip_runtime.h>

// FogAdversary: diamond-square fractal fog + blend.
// Kernel 1 (fog_coarse): levels 0..6 (step 256..4) per batch, entirely in LDS
//   (final dense 128x128 lattice = map positions (2i,2j)), dumped to d_ws.
// Kernel 2 (fog_apply): level 7 (step=2) computed on the fly per 32-row tile,
//   fused with crop (PAD=16) and the fog blend over 3 channels.
//
// Map conventions (per reference):
//   level k: step s=256>>k, h=s/2, wibble w_k = 2^-k, fog vars v=3k..3k+2
//   center  m[h::s, h::s] = (C[i,j]+C[i+1,j]+C[i,j+1]+C[i+1,j+1])/4 + w*f[3k]
//   lt      m[0::s, h::s] = (D[i,j]+D[i-1,j]+C[i,j]+C[i,j+1])/4     + w*f[3k+1]
//   tt      m[h::s, 0::s] = (D[i,j]+D[i,j-1]+C[i,j]+C[i+1,j])/4     + w*f[3k+2]
//   (all indices mod n; crop region never wraps rows/cols at level 7)

#define MAPB 128

struct FogPtrs { const float* f[24]; };

__global__ __launch_bounds__(256) void fog_coarse(FogPtrs fp, float* __restrict__ Cout) {
    __shared__ float Bm[MAPB * MAPB];          // 64 KB: values at final positions (2i,2j)
    const int b = blockIdx.x;
    const int t = threadIdx.x;
    if (t == 0) Bm[0] = 0.0f;                  // only lattice point never written by a level
    __syncthreads();
    float w = 1.0f;
    for (int k = 0; k < 7; ++k) {
        const int n = 1 << k, mask = n - 1;
        const int S = MAPB >> k, H = S >> 1;   // buffer stride / half-offset
        const int nn = n * n;
        const float* __restrict__ f0 = fp.f[3 * k]     + b * nn;
        const float* __restrict__ f1 = fp.f[3 * k + 1] + b * nn;
        const float* __restrict__ f2 = fp.f[3 * k + 2] + b * nn;
        // diamond (centers)
        for (int idx = t; idx < nn; idx += 256) {
            const int i = idx >> k, j = idx & mask;
            const int i1 = (i + 1) & mask, j1 = (j + 1) & mask;
            const float c00 = Bm[i  * S * MAPB + j  * S];
            const float c10 = Bm[i1 * S * MAPB + j  * S];
            const float c01 = Bm[i  * S * MAPB + j1 * S];
            const float c11 = Bm[i1 * S * MAPB + j1 * S];
            Bm[(i * S + H) * MAPB + j * S + H] = (c00 + c10 + c01 + c11) * 0.25f + w * f0[idx];
        }
        __syncthreads();
        // square (edges): reads corners+centers only, writes edges -> no race
        for (int idx = t; idx < nn; idx += 256) {
            const int i = idx >> k, j = idx & mask;
            const int i1 = (i + 1) & mask, j1 = (j + 1) & mask;
            const int im = (i - 1) & mask, jm = (j - 1) & mask;
            const float dij = Bm[(i  * S + H) * MAPB + j  * S + H];
            const float dmi = Bm[(im * S + H) * MAPB + j  * S + H];
            const float dmj = Bm[(i  * S + H) * MAPB + jm * S + H];
            const float c00 = Bm[i  * S * MAPB + j  * S];
            const float c01 = Bm[i  * S * MAPB + j1 * S];
            const float c10 = Bm[i1 * S * MAPB + j  * S];
            Bm[i * S * MAPB + j * S + H]       = (dij + dmi + c00 + c01) * 0.25f + w * f1[idx];
            Bm[(i * S + H) * MAPB + j * S]     = (dij + dmj + c00 + c10) * 0.25f + w * f2[idx];
        }
        __syncthreads();
        w *= 0.5f;
    }
    // dump dense 128x128 lattice
    float4* __restrict__ dst = (float4*)(Cout + (size_t)b * (MAPB * MAPB));
    const float4* src = (const float4*)Bm;
    for (int idx = t; idx < MAPB * MAPB / 4; idx += 256) dst[idx] = src[idx];
}

// Tile: one batch x 32 output rows x 224 cols. Level-7 needs C rows
// [ci0, ci0+17] (18) and D (center) rows [ci0, ci0+16] (17), ci0 = r0/2+7.
__global__ __launch_bounds__(256) void fog_apply(
    const float* __restrict__ inp,
    const float* __restrict__ Cg,
    const float* __restrict__ f21, const float* __restrict__ f22, const float* __restrict__ f23,
    float* __restrict__ out)
{
    __shared__ float sC[18 * 128];   //  9.0 KB corners
    __shared__ float sD[17 * 128];   //  8.5 KB centers
    __shared__ float sF[32 * 224];   // 28.0 KB fog tile
    const int b  = blockIdx.y;
    const int r0 = blockIdx.x * 32;          // output row base (0..192)
    const int t  = threadIdx.x;
    const int ci0 = (r0 >> 1) + 7;           // first corner row needed

    const float* __restrict__ Cb = Cg + (size_t)b * 16384 + ci0 * 128;
    for (int idx = t; idx < 18 * 128; idx += 256) sC[idx] = Cb[idx];
    __syncthreads();

    const float w7 = 0.0078125f;             // wibble at level 7 = 2^-7
    const float* __restrict__ f21b = f21 + (size_t)b * 16384 + ci0 * 128;
    for (int idx = t; idx < 17 * 128; idx += 256) {
        const int di = idx >> 7, j = idx & 127;
        const int j1 = (j + 1) & 127;        // col wrap is real map semantics (unused cols harmless)
        sD[idx] = (sC[di * 128 + j] + sC[(di + 1) * 128 + j] +
                   sC[di * 128 + j1] + sC[(di + 1) * 128 + j1]) * 0.25f
                  + w7 * f21b[idx];
    }
    __syncthreads();

    // one 2x2 output quad per work item: corner, lt, tt, center -> no divergence
    const float* __restrict__ f22b = f22 + (size_t)b * 16384;
    const float* __restrict__ f23b = f23 + (size_t)b * 16384;
    for (int q = t; q < 16 * 112; q += 256) {       // 1792 = 7 iters exactly
        const int qr = q / 112;
        const int qc = q - qr * 112;
        const int di = qr + 1;                      // local corner/center row
        const int j  = qc + 8;                      // global col index (8..119)
        const int gi = ci0 + di;                    // global row index
        const float c00 = sC[di * 128 + j];
        const float d11 = sD[di * 128 + j];
        const float mlt = (d11 + sD[(di - 1) * 128 + j] + c00 + sC[di * 128 + j + 1]) * 0.25f
                          + w7 * f22b[gi * 128 + j];
        const float mtt = (d11 + sD[di * 128 + j - 1] + c00 + sC[(di + 1) * 128 + j]) * 0.25f
                          + w7 * f23b[gi * 128 + j];
        const int fr = 2 * qr, fc = 2 * qc;
        float2 top, bot;
        top.x = fminf(fabsf(c00), 1.0f);
        top.y = fminf(fabsf(mlt), 1.0f);
        bot.x = fminf(fabsf(mtt), 1.0f);
        bot.y = fminf(fabsf(d11), 1.0f);
        *(float2*)&sF[fr * 224 + fc]       = top;
        *(float2*)&sF[(fr + 1) * 224 + fc] = bot;
    }
    __syncthreads();

    // blend: tile rows are contiguous both in LDS and in global -> linear float4
    #pragma unroll
    for (int ch = 0; ch < 3; ++ch) {
        const float g = (ch == 0) ? 0.485f : ((ch == 1) ? 0.45f : 0.406f);
        const float4* __restrict__ ip = (const float4*)(inp + ((size_t)(b * 3 + ch) * 224 + r0) * 224);
        float4* __restrict__ op = (float4*)(out + ((size_t)(b * 3 + ch) * 224 + r0) * 224);
        for (int v = t; v < 32 * 56; v += 256) {    // 1792 = 7 iters exactly
            float4 x = ip[v];
            const float4 f = *(const float4*)&sF[v * 4];
            float4 o;
            o.x = x.x * (1.0f - f.x) + f.x * g;
            o.y = x.y * (1.0f - f.y) + f.y * g;
            o.z = x.z * (1.0f - f.z) + f.z * g;
            o.w = x.w * (1.0f - f.w) + f.w * g;
            op[v] = o;
        }
    }
}

extern "C" void kernel_launch(void* const* d_in, const int* in_sizes, int n_in,
                              void* d_out, int out_size, void* d_ws, size_t ws_size,
                              hipStream_t stream) {
    (void)in_sizes; (void)n_in; (void)out_size; (void)ws_size;
    const float* inp = (const float*)d_in[0];
    FogPtrs fp;
    for (int v = 0; v < 24; ++v) fp.f[v] = (const float*)d_in[1 + v];
    float* Cg = (float*)d_ws;                       // 256*128*128*4 = 16.8 MB scratch

    fog_coarse<<<dim3(256), dim3(256), 0, stream>>>(fp, Cg);
    fog_apply<<<dim3(7, 256), dim3(256), 0, stream>>>(
        inp, Cg, fp.f[21], fp.f[22], fp.f[23], (float*)d_out);
}

// Round 2
// 359.594 us; speedup vs baseline: 1.1145x; 1.1145x over previous
//
#include <hip/hip_runtime.h>

// FogAdversary: diamond-square fractal fog + blend.
// Kernel 1 (fog_coarse): levels 0..6 (step 256..4) per batch, entirely in LDS
//   (final dense 128x128 lattice = map positions (2i,2j)), dumped to d_ws.
//   1024 threads/block for latency hiding across the 14 barrier phases.
// Kernel 2 (fog_apply): level 7 (step=2) computed on the fly per 32-row tile,
//   fused with crop (PAD=16) and blend. No sF staging: fog values stay in
//   registers, blend uses direct float2 global I/O. LDS 17.9KB -> 8 blocks/CU.
//
// Map conventions (per reference):
//   level k: step s=256>>k, h=s/2, wibble w_k = 2^-k, fog vars v=3k..3k+2
//   center  m[h::s, h::s] = (C[i,j]+C[i+1,j]+C[i,j+1]+C[i+1,j+1])/4 + w*f[3k]
//   lt      m[0::s, h::s] = (D[i,j]+D[i-1,j]+C[i,j]+C[i,j+1])/4     + w*f[3k+1]
//   tt      m[h::s, 0::s] = (D[i,j]+D[i,j-1]+C[i,j]+C[i+1,j])/4     + w*f[3k+2]
//   (indices mod n; crop region never wraps rows/cols at level 7)

#define MAPB 128

struct FogPtrs { const float* f[24]; };

__global__ __launch_bounds__(1024) void fog_coarse(FogPtrs fp, float* __restrict__ Cout) {
    __shared__ float Bm[MAPB * MAPB];          // 64 KB: values at final positions (2i,2j)
    const int b = blockIdx.x;
    const int t = threadIdx.x;
    if (t == 0) Bm[0] = 0.0f;                  // only lattice point never written by a level
    __syncthreads();
    float w = 1.0f;
    for (int k = 0; k < 7; ++k) {
        const int n = 1 << k, mask = n - 1;
        const int S = MAPB >> k, H = S >> 1;   // buffer stride / half-offset
        const int nn = n * n;
        const float* __restrict__ f0 = fp.f[3 * k]     + b * nn;
        const float* __restrict__ f1 = fp.f[3 * k + 1] + b * nn;
        const float* __restrict__ f2 = fp.f[3 * k + 2] + b * nn;
        // diamond (centers)
        for (int idx = t; idx < nn; idx += 1024) {
            const int i = idx >> k, j = idx & mask;
            const int i1 = (i + 1) & mask, j1 = (j + 1) & mask;
            const float c00 = Bm[i  * S * MAPB + j  * S];
            const float c10 = Bm[i1 * S * MAPB + j  * S];
            const float c01 = Bm[i  * S * MAPB + j1 * S];
            const float c11 = Bm[i1 * S * MAPB + j1 * S];
            Bm[(i * S + H) * MAPB + j * S + H] = (c00 + c10 + c01 + c11) * 0.25f + w * f0[idx];
        }
        __syncthreads();
        // square (edges): reads corners+centers only, writes edges -> no race
        for (int idx = t; idx < nn; idx += 1024) {
            const int i = idx >> k, j = idx & mask;
            const int i1 = (i + 1) & mask, j1 = (j + 1) & mask;
            const int im = (i - 1) & mask, jm = (j - 1) & mask;
            const float dij = Bm[(i  * S + H) * MAPB + j  * S + H];
            const float dmi = Bm[(im * S + H) * MAPB + j  * S + H];
            const float dmj = Bm[(i  * S + H) * MAPB + jm * S + H];
            const float c00 = Bm[i  * S * MAPB + j  * S];
            const float c01 = Bm[i  * S * MAPB + j1 * S];
            const float c10 = Bm[i1 * S * MAPB + j  * S];
            Bm[i * S * MAPB + j * S + H]       = (dij + dmi + c00 + c01) * 0.25f + w * f1[idx];
            Bm[(i * S + H) * MAPB + j * S]     = (dij + dmj + c00 + c10) * 0.25f + w * f2[idx];
        }
        __syncthreads();
        w *= 0.5f;
    }
    // dump dense 128x128 lattice
    float4* __restrict__ dst = (float4*)(Cout + (size_t)b * (MAPB * MAPB));
    const float4* src = (const float4*)Bm;
    for (int idx = t; idx < MAPB * MAPB / 4; idx += 1024) dst[idx] = src[idx];
}

// Tile: one batch x 32 output rows x 224 cols. Level-7 needs C rows
// [ci0, ci0+17] (18) and D (center) rows [ci0, ci0+16] (17), ci0 = r0/2+7.
// LDS = 17.9 KB -> 8 blocks/CU -> 32 waves/CU (100% occupancy cap).
__global__ __launch_bounds__(256) void fog_apply(
    const float* __restrict__ inp,
    const float* __restrict__ Cg,
    const float* __restrict__ f21, const float* __restrict__ f22, const float* __restrict__ f23,
    float* __restrict__ out)
{
    __shared__ float sC[18 * 128];   //  9.0 KB corners
    __shared__ float sD[17 * 128];   //  8.5 KB centers
    const int b  = blockIdx.y;
    const int r0 = blockIdx.x * 32;          // output row base (0..192)
    const int t  = threadIdx.x;
    const int ci0 = (r0 >> 1) + 7;           // first corner row needed

    const float* __restrict__ Cb = Cg + (size_t)b * 16384 + ci0 * 128;
    for (int idx = t; idx < 18 * 128; idx += 256) sC[idx] = Cb[idx];
    __syncthreads();

    const float w7 = 0.0078125f;             // wibble at level 7 = 2^-7
    const float* __restrict__ f21b = f21 + (size_t)b * 16384 + ci0 * 128;
    for (int idx = t; idx < 17 * 128; idx += 256) {
        const int di = idx >> 7, j = idx & 127;
        const int j1 = (j + 1) & 127;        // col wrap is real map semantics (unused cols harmless)
        sD[idx] = (sC[di * 128 + j] + sC[(di + 1) * 128 + j] +
                   sC[di * 128 + j1] + sC[(di + 1) * 128 + j1]) * 0.25f
                  + w7 * f21b[idx];
    }
    __syncthreads();

    // one 2x2 output quad per work item: corner, lt, tt, center -> no divergence.
    // Fog stays in registers; blend is direct float2 global I/O (coalesced:
    // consecutive lanes -> consecutive float2 within a row segment).
    const float* __restrict__ f22b = f22 + (size_t)b * 16384;
    const float* __restrict__ f23b = f23 + (size_t)b * 16384;
    for (int q = t; q < 16 * 112; q += 256) {       // 1792 = 7 iters exactly
        const int qr = q / 112;
        const int qc = q - qr * 112;
        const int di = qr + 1;                      // local corner/center row
        const int j  = qc + 8;                      // global col index (8..119)
        const int gi = ci0 + di;                    // global row index
        const float c00 = sC[di * 128 + j];
        const float d11 = sD[di * 128 + j];
        const float mlt = (d11 + sD[(di - 1) * 128 + j] + c00 + sC[di * 128 + j + 1]) * 0.25f
                          + w7 * f22b[gi * 128 + j];
        const float mtt = (d11 + sD[di * 128 + j - 1] + c00 + sC[(di + 1) * 128 + j]) * 0.25f
                          + w7 * f23b[gi * 128 + j];
        const float f00 = fminf(fabsf(c00), 1.0f);
        const float f01 = fminf(fabsf(mlt), 1.0f);
        const float f10 = fminf(fabsf(mtt), 1.0f);
        const float f11 = fminf(fabsf(d11), 1.0f);

        const int row0 = r0 + 2 * qr;               // output row (0..222)
        const int col  = 2 * qc;                    // output col (0..222)
        #pragma unroll
        for (int ch = 0; ch < 3; ++ch) {
            const float g = (ch == 0) ? 0.485f : ((ch == 1) ? 0.45f : 0.406f);
            const size_t base = ((size_t)(b * 3 + ch) * 224 + row0) * 224 + col;
            const float2 x0 = *(const float2*)(inp + base);
            const float2 x1 = *(const float2*)(inp + base + 224);
            float2 o0, o1;
            o0.x = x0.x * (1.0f - f00) + f00 * g;
            o0.y = x0.y * (1.0f - f01) + f01 * g;
            o1.x = x1.x * (1.0f - f10) + f10 * g;
            o1.y = x1.y * (1.0f - f11) + f11 * g;
            *(float2*)(out + base)       = o0;
            *(float2*)(out + base + 224) = o1;
        }
    }
}

extern "C" void kernel_launch(void* const* d_in, const int* in_sizes, int n_in,
                              void* d_out, int out_size, void* d_ws, size_t ws_size,
                              hipStream_t stream) {
    (void)in_sizes; (void)n_in; (void)out_size; (void)ws_size;
    const float* inp = (const float*)d_in[0];
    FogPtrs fp;
    for (int v = 0; v < 24; ++v) fp.f[v] = (const float*)d_in[1 + v];
    float* Cg = (float*)d_ws;                       // 256*128*128*4 = 16.8 MB scratch

    fog_coarse<<<dim3(256), dim3(1024), 0, stream>>>(fp, Cg);
    fog_apply<<<dim3(7, 256), dim3(256), 0, stream>>>(
        inp, Cg, fp.f[21], fp.f[22], fp.f[23], (float*)d_out);
}

// Round 3
// 355.140 us; speedup vs baseline: 1.1285x; 1.0125x over previous
//
#include <hip/hip_runtime.h>

// FogAdversary: diamond-square fractal fog + blend.
// Kernel 1 (fog_coarse): levels 0..6 per batch in 64KB LDS; all fog-var global
//   loads PREFETCHED into registers at entry so the 14 barrier phases have no
//   global latency on the critical path. Dense 128x128 lattice -> d_ws.
// Kernel 2 (fog_apply): level 7 (step=2) on the fly per 56-row tile, fused with
//   crop (PAD=16) and blend. 512 thr, 30.2KB LDS -> exactly 4 blocks/CU,
//   grid 4x256 = 1024 = full residency. Each thread: 2 adjacent quads ->
//   all image I/O is aligned float4.
//
// Map conventions (per reference):
//   level k: step s=256>>k, h=s/2, wibble w_k = 2^-k, fog vars v=3k..3k+2
//   center  m[h::s, h::s] = (C[i,j]+C[i+1,j]+C[i,j+1]+C[i+1,j+1])/4 + w*f[3k]
//   lt      m[0::s, h::s] = (D[i,j]+D[i-1,j]+C[i,j]+C[i,j+1])/4     + w*f[3k+1]
//   tt      m[h::s, 0::s] = (D[i,j]+D[i,j-1]+C[i,j]+C[i+1,j])/4     + w*f[3k+2]
//   (indices mod n; crop region never wraps rows/cols at level 7)

#define MAPB 128

struct FogPtrs { const float* f[24]; };

__global__ __launch_bounds__(1024) void fog_coarse(FogPtrs fp, float* __restrict__ Cout) {
    __shared__ float Bm[MAPB * MAPB];          // 64 KB: values at final positions (2i,2j)
    const int b = blockIdx.x;
    const int t = threadIdx.x;

    // ---- prefetch ALL fog perturbations into registers (independent loads) ----
    float pf0[6], pf1[6], pf2[6];              // levels 0..5: one masked item/thread
    #pragma unroll
    for (int k = 0; k < 6; ++k) {
        const int nn = 1 << (2 * k);
        if (t < nn) {
            pf0[k] = fp.f[3 * k]    [(size_t)b * nn + t];
            pf1[k] = fp.f[3 * k + 1][(size_t)b * nn + t];
            pf2[k] = fp.f[3 * k + 2][(size_t)b * nn + t];
        }
    }
    float q0[4], q1[4], q2[4];                 // level 6: nn=4096 -> 4 items/thread
    {
        const float* __restrict__ f0 = fp.f[18] + (size_t)b * 4096;
        const float* __restrict__ f1 = fp.f[19] + (size_t)b * 4096;
        const float* __restrict__ f2 = fp.f[20] + (size_t)b * 4096;
        #pragma unroll
        for (int it = 0; it < 4; ++it) {
            q0[it] = f0[t + it * 1024];
            q1[it] = f1[t + it * 1024];
            q2[it] = f2[t + it * 1024];
        }
    }
    if (t == 0) Bm[0] = 0.0f;                  // only lattice point never written
    __syncthreads();

    float w = 1.0f;
    #pragma unroll
    for (int k = 0; k < 6; ++k) {              // levels 0..5: t < nn (<=1024) active
        const int n = 1 << k, mask = n - 1;
        const int S = MAPB >> k, H = S >> 1;
        const int nn = n * n;
        if (t < nn) {
            const int i = t >> k, j = t & mask;
            const int i1 = (i + 1) & mask, j1 = (j + 1) & mask;
            const float c00 = Bm[i  * S * MAPB + j  * S];
            const float c10 = Bm[i1 * S * MAPB + j  * S];
            const float c01 = Bm[i  * S * MAPB + j1 * S];
            const float c11 = Bm[i1 * S * MAPB + j1 * S];
            Bm[(i * S + H) * MAPB + j * S + H] = (c00 + c10 + c01 + c11) * 0.25f + w * pf0[k];
        }
        __syncthreads();
        if (t < nn) {
            const int i = t >> k, j = t & mask;
            const int i1 = (i + 1) & mask, j1 = (j + 1) & mask;
            const int im = (i - 1) & mask, jm = (j - 1) & mask;
            const float dij = Bm[(i  * S + H) * MAPB + j  * S + H];
            const float dmi = Bm[(im * S + H) * MAPB + j  * S + H];
            const float dmj = Bm[(i  * S + H) * MAPB + jm * S + H];
            const float c00 = Bm[i  * S * MAPB + j  * S];
            const float c01 = Bm[i  * S * MAPB + j1 * S];
            const float c10 = Bm[i1 * S * MAPB + j  * S];
            Bm[i * S * MAPB + j * S + H]   = (dij + dmi + c00 + c01) * 0.25f + w * pf1[k];
            Bm[(i * S + H) * MAPB + j * S] = (dij + dmj + c00 + c10) * 0.25f + w * pf2[k];
        }
        __syncthreads();
        w *= 0.5f;
    }
    // level 6: n=64, S=2, H=1, nn=4096, w = 2^-6
    {
        const float w6 = 0.015625f;
        #pragma unroll
        for (int it = 0; it < 4; ++it) {
            const int idx = t + it * 1024;
            const int i = idx >> 6, j = idx & 63;
            const int i1 = (i + 1) & 63, j1 = (j + 1) & 63;
            const float c00 = Bm[i  * 2 * MAPB + j  * 2];
            const float c10 = Bm[i1 * 2 * MAPB + j  * 2];
            const float c01 = Bm[i  * 2 * MAPB + j1 * 2];
            const float c11 = Bm[i1 * 2 * MAPB + j1 * 2];
            Bm[(i * 2 + 1) * MAPB + j * 2 + 1] = (c00 + c10 + c01 + c11) * 0.25f + w6 * q0[it];
        }
        __syncthreads();
        #pragma unroll
        for (int it = 0; it < 4; ++it) {
            const int idx = t + it * 1024;
            const int i = idx >> 6, j = idx & 63;
            const int i1 = (i + 1) & 63, j1 = (j + 1) & 63;
            const int im = (i - 1) & 63, jm = (j - 1) & 63;
            const float dij = Bm[(i  * 2 + 1) * MAPB + j  * 2 + 1];
            const float dmi = Bm[(im * 2 + 1) * MAPB + j  * 2 + 1];
            const float dmj = Bm[(i  * 2 + 1) * MAPB + jm * 2 + 1];
            const float c00 = Bm[i  * 2 * MAPB + j  * 2];
            const float c01 = Bm[i  * 2 * MAPB + j1 * 2];
            const float c10 = Bm[i1 * 2 * MAPB + j  * 2];
            Bm[i * 2 * MAPB + j * 2 + 1]   = (dij + dmi + c00 + c01) * 0.25f + w6 * q1[it];
            Bm[(i * 2 + 1) * MAPB + j * 2] = (dij + dmj + c00 + c10) * 0.25f + w6 * q2[it];
        }
        __syncthreads();
    }
    // dump dense 128x128 lattice (4096 float4)
    float4* __restrict__ dst = (float4*)(Cout + (size_t)b * (MAPB * MAPB));
    const float4* src = (const float4*)Bm;
    #pragma unroll
    for (int it = 0; it < 4; ++it) dst[t + it * 1024] = src[t + it * 1024];
}

// Tile: one batch x 56 output rows. Needs C rows [ci0, ci0+29] (30) and
// D rows [ci0, ci0+28] (29), ci0 = r0/2+7. LDS 30.2KB, 512 thr ->
// 4 blocks/CU (LDS 120.8KB, 32 waves). Grid 4x256 = 1024 = exact residency.
__global__ __launch_bounds__(512) void fog_apply(
    const float* __restrict__ inp,
    const float* __restrict__ Cg,
    const float* __restrict__ f21, const float* __restrict__ f22, const float* __restrict__ f23,
    float* __restrict__ out)
{
    __shared__ __align__(16) float sC[30 * 128];   // 15.0 KB corners
    __shared__ __align__(16) float sD[29 * 128];   // 14.5 KB centers
    const int b  = blockIdx.y;
    const int r0 = blockIdx.x * 56;          // output row base (0,56,112,168)
    const int t  = threadIdx.x;
    const int ci0 = (r0 >> 1) + 7;           // first corner row needed

    // load 30 C rows = 960 float4 (offset multiple of 128 floats -> aligned)
    const float4* __restrict__ Cb4 = (const float4*)(Cg + (size_t)b * 16384 + (size_t)ci0 * 128);
    float4* __restrict__ sC4 = (float4*)sC;
    sC4[t] = Cb4[t];
    if (t < 448) sC4[t + 512] = Cb4[t + 512];
    __syncthreads();

    const float w7 = 0.0078125f;             // wibble at level 7 = 2^-7
    const float* __restrict__ f21b = f21 + (size_t)b * 16384 + (size_t)ci0 * 128;
    for (int idx = t; idx < 29 * 128; idx += 512) {
        const int di = idx >> 7, j = idx & 127;
        const int j1 = (j + 1) & 127;        // col wrap = real map semantics (unused cols harmless)
        sD[idx] = (sC[di * 128 + j] + sC[(di + 1) * 128 + j] +
                   sC[di * 128 + j1] + sC[(di + 1) * 128 + j1]) * 0.25f
                  + w7 * f21b[idx];
    }
    __syncthreads();

    // Pair = two adjacent 2x2 quads -> 4 cols x 2 rows -> float4 I/O.
    // 28 quad-rows x 56 pairs = 1568 items.
    const float* __restrict__ f22b = f22 + (size_t)b * 16384;
    const float* __restrict__ f23b = f23 + (size_t)b * 16384;
    for (int p = t; p < 28 * 56; p += 512) {
        const int pr = p / 56;
        const int pc = p - pr * 56;
        const int di = pr + 1;                      // local C/D row
        const int j0 = 2 * pc + 8;                  // map col (8..118, even)
        const int gi = ci0 + di;                    // global map row
        const float c0  = sC[di * 128 + j0];
        const float c1  = sC[di * 128 + j0 + 1];
        const float c2  = sC[di * 128 + j0 + 2];
        const float cb0 = sC[(di + 1) * 128 + j0];
        const float cb1 = sC[(di + 1) * 128 + j0 + 1];
        const float dm  = sD[di * 128 + j0 - 1];
        const float d0  = sD[di * 128 + j0];
        const float d1  = sD[di * 128 + j0 + 1];
        const float du0 = sD[(di - 1) * 128 + j0];
        const float du1 = sD[(di - 1) * 128 + j0 + 1];
        const float2 v22 = *(const float2*)(f22b + (size_t)gi * 128 + j0);  // 8B aligned
        const float2 v23 = *(const float2*)(f23b + (size_t)gi * 128 + j0);
        const float lt0 = (d0 + du0 + c0 + c1) * 0.25f + w7 * v22.x;
        const float lt1 = (d1 + du1 + c1 + c2) * 0.25f + w7 * v22.y;
        const float tt0 = (d0 + dm + c0 + cb0) * 0.25f + w7 * v23.x;
        const float tt1 = (d1 + d0 + c1 + cb1) * 0.25f + w7 * v23.y;
        // fog factors: top row [corner, lt, corner, lt]; bottom [tt, center, tt, center]
        const float fa = fminf(fabsf(c0),  1.0f);
        const float fb = fminf(fabsf(lt0), 1.0f);
        const float fc = fminf(fabsf(c1),  1.0f);
        const float fd = fminf(fabsf(lt1), 1.0f);
        const float fe = fminf(fabsf(tt0), 1.0f);
        const float ff = fminf(fabsf(d0),  1.0f);
        const float fg = fminf(fabsf(tt1), 1.0f);
        const float fh = fminf(fabsf(d1),  1.0f);

        const int orow = r0 + 2 * pr;               // output row (0..222)
        const int ocol = 4 * pc;                    // output col (0..220), %4==0
        #pragma unroll
        for (int ch = 0; ch < 3; ++ch) {
            const float g = (ch == 0) ? 0.485f : ((ch == 1) ? 0.45f : 0.406f);
            const size_t base = ((size_t)(b * 3 + ch) * 224 + orow) * 224 + ocol;
            const float4 x0 = *(const float4*)(inp + base);
            const float4 x1 = *(const float4*)(inp + base + 224);
            float4 o0, o1;
            o0.x = x0.x * (1.0f - fa) + fa * g;
            o0.y = x0.y * (1.0f - fb) + fb * g;
            o0.z = x0.z * (1.0f - fc) + fc * g;
            o0.w = x0.w * (1.0f - fd) + fd * g;
            o1.x = x1.x * (1.0f - fe) + fe * g;
            o1.y = x1.y * (1.0f - ff) + ff * g;
            o1.z = x1.z * (1.0f - fg) + fg * g;
            o1.w = x1.w * (1.0f - fh) + fh * g;
            *(float4*)(out + base)       = o0;
            *(float4*)(out + base + 224) = o1;
        }
    }
}

extern "C" void kernel_launch(void* const* d_in, const int* in_sizes, int n_in,
                              void* d_out, int out_size, void* d_ws, size_t ws_size,
                              hipStream_t stream) {
    (void)in_sizes; (void)n_in; (void)out_size; (void)ws_size;
    const float* inp = (const float*)d_in[0];
    FogPtrs fp;
    for (int v = 0; v < 24; ++v) fp.f[v] = (const float*)d_in[1 + v];
    float* Cg = (float*)d_ws;                       // 256*128*128*4 = 16.8 MB scratch

    fog_coarse<<<dim3(256), dim3(1024), 0, stream>>>(fp, Cg);
    fog_apply<<<dim3(4, 256), dim3(512), 0, stream>>>(
        inp, Cg, fp.f[21], fp.f[22], fp.f[23], (float*)d_out);
}